// Round 9
// baseline (193.478 us; speedup 1.0000x reference)
//
#include <hip/hip_runtime.h>
#include <math.h>

#define N 8192
#define C 10
#define NUM_ITERS 5
#define FBLOCK 1024        /* 16 waves; 2 blocks/CU -> 8 waves/SIMD (VGPR<=64) */
#define IBLK 16            /* i's per block */
#define NBLK (N / IBLK)    /* 512 blocks = 2 per CU */
#define JW (N / 16)        /* 512 j's per wave (contiguous slice) */
#define NS (JW / 32)       /* 16 s-iters per wave, 32 j's each */
#define LOG2E 1.44269504088896340736f
#define C3 (LOG2E / 64.0f)

typedef _Float16 half8 __attribute__((ext_vector_type(8)));
typedef _Float16 half4 __attribute__((ext_vector_type(4)));
typedef _Float16 half2 __attribute__((ext_vector_type(2)));
typedef float f32x4 __attribute__((ext_vector_type(4)));

// ws layout:
//   ajs half8[N]        128KB : j-side spatial aug [f*C3 x3, 0, 0,0,-h3*C3, 1]
//   ajb half8[N]        128KB : j-side bilateral aug [f*L2E x6, -h6*L2E, 1]
//   pf0 f16[N/16][16][16] 256KB : probs, J-TILED (tile jt, row c, col j&15); rows 10..15 zero
//   pf1 f16[N/16][16][16] 256KB : ping-pong partner
#define WS_AJS 0
#define WS_AJB (N * 16)
#define WS_PF0 (N * 32)
#define WS_PF1 (N * 64)
#define PFIDX(n, c) ((((n) >> 4) * 16 + (c)) * 16 + ((n) & 15))

static __device__ __forceinline__ half4 expcvt(f32x4 d) {
    float e0 = __builtin_amdgcn_exp2f(d[0]);
    float e1 = __builtin_amdgcn_exp2f(d[1]);
    float e2 = __builtin_amdgcn_exp2f(d[2]);
    float e3 = __builtin_amdgcn_exp2f(d[3]);
    half2 lo = __builtin_bit_cast(half2, __builtin_amdgcn_cvt_pkrtz(e0, e1));
    half2 hi = __builtin_bit_cast(half2, __builtin_amdgcn_cvt_pkrtz(e2, e3));
    half4 r = {lo[0], lo[1], hi[0], hi[1]};
    return r;
}

// one group: A-frag (16 j's) x 1 i-subtile -> exp -> GEMM2 accumulate.
// Short chain, minimal live temps (1 f32x4 + 1 half4).
#define GROUP(AF, PF_, B1, ACC)                                                      \
    {                                                                                \
        f32x4 _d = __builtin_amdgcn_mfma_f32_16x16x16f16(AF, B1, zero, 0, 0, 0);     \
        half4 _w = expcvt(_d);                                                       \
        ACC = __builtin_amdgcn_mfma_f32_16x16x16f16(_w, PF_, ACC, 0, 0, 0);          \
    }

// once per launch: aug features + softmax(unaries) -> pf0 (tiled); zero rows 10..15 both
__global__ __launch_bounds__(256) void init_kernel(
    const float* __restrict__ unaries, const float* __restrict__ feat,
    half8* __restrict__ ajs8, half8* __restrict__ ajb8,
    _Float16* __restrict__ pf0, _Float16* __restrict__ pf1) {
    int n = blockIdx.x * 256 + threadIdx.x;
    float f6[6];
#pragma unroll
    for (int d = 0; d < 6; ++d) f6[d] = feat[d * N + n];
    float h3 = 0.5f * (f6[0] * f6[0] + f6[1] * f6[1] + f6[2] * f6[2]);
    float h6v = h3 + 0.5f * (f6[3] * f6[3] + f6[4] * f6[4] + f6[5] * f6[5]);
    half8 a = {};
    a[0] = (_Float16)(f6[0] * C3);
    a[1] = (_Float16)(f6[1] * C3);
    a[2] = (_Float16)(f6[2] * C3);
    a[6] = (_Float16)(-h3 * C3);
    a[7] = (_Float16)1.0f;
    ajs8[n] = a;
    half8 b;
#pragma unroll
    for (int d = 0; d < 6; ++d) b[d] = (_Float16)(f6[d] * LOG2E);
    b[6] = (_Float16)(-h6v * LOG2E);
    b[7] = (_Float16)1.0f;
    ajb8[n] = b;

    float q[C];
#pragma unroll
    for (int c = 0; c < C; ++c) q[c] = unaries[c * N + n];
    float m = q[0];
#pragma unroll
    for (int c = 1; c < C; ++c) m = fmaxf(m, q[c]);
    float e[C], s = 0.0f;
#pragma unroll
    for (int c = 0; c < C; ++c) {
        e[c] = __builtin_amdgcn_exp2f((q[c] - m) * LOG2E);
        s += e[c];
    }
    float inv = 1.0f / s;
#pragma unroll
    for (int c = 0; c < C; ++c) pf0[PFIDX(n, c)] = (_Float16)(e[c] * inv);
#pragma unroll
    for (int c = C; c < 16; ++c) {
        pf0[PFIDX(n, c)] = (_Float16)0.0f;
        pf1[PFIDX(n, c)] = (_Float16)0.0f;
    }
}

// one dispatch per CRF iteration: block owns 16 i's; wave w free-runs its
// contiguous 512-j slice with direct global->register operand fetch (coalesced,
// L2-resident; latency hidden by 8 waves/SIMD TLP). No LDS/barriers in main
// loop. LDS (32KB) only for cross-wave reduction + in-block combine/softmax.
__global__ __launch_bounds__(FBLOCK, 8) void fused_kernel(
    const float* __restrict__ unaries, const float* __restrict__ feat,
    const float* __restrict__ SW, const float* __restrict__ BW,
    const float* __restrict__ CM,
    const half4* __restrict__ ajs_g, const half4* __restrict__ ajb_g,
    const _Float16* __restrict__ pf_in, _Float16* __restrict__ pf_out,
    float* __restrict__ out, int is_last) {
    __shared__ float rbuf[16 * 512];   // 32 KB, epilogue only
    int t = threadIdx.x;
    int i0 = blockIdx.x * IBLK;
    int lane = t & 63;
    int w = t >> 6;            // wave id 0..15
    int il = lane & 15;
    int quad = lane >> 4;
    int h = quad & 1;
    bool klo = (quad < 2);
    const half4 hz = {};
    const f32x4 zero = {0.f, 0.f, 0.f, 0.f};

    // ---- i-side B1 fragments (16 i's, 1 subtile), per filter ----
    half4 b1s, b1b;
    {
        int i = i0 + il;
        float g0 = feat[0 * N + i], g1 = feat[1 * N + i], g2 = feat[2 * N + i];
        float g3 = feat[3 * N + i], g4 = feat[4 * N + i], g5 = feat[5 * N + i];
        float h3 = 0.5f * (g0 * g0 + g1 * g1 + g2 * g2);
        float h6v = h3 + 0.5f * (g3 * g3 + g4 * g4 + g5 * g5);
        half4 slo = {(_Float16)g0, (_Float16)g1, (_Float16)g2, (_Float16)0.0f};
        half4 shi = {(_Float16)0.0f, (_Float16)0.0f, (_Float16)1.0f, (_Float16)(-h3 * C3)};
        half4 blo = {(_Float16)g0, (_Float16)g1, (_Float16)g2, (_Float16)g3};
        half4 bhi = {(_Float16)g4, (_Float16)g5, (_Float16)1.0f, (_Float16)(-h6v * LOG2E)};
        b1s = klo ? (h ? shi : slo) : hz;
        b1b = klo ? (h ? bhi : blo) : hz;
    }

    f32x4 acc_s = zero, acc_b = zero;

    int jw = w * JW;   // wave's global j base
    const half4* pfv = (const half4*)pf_in;   // half4 idx = (jt*16 + c)*4 + quad

#pragma unroll 2
    for (int k = 0; k < NS; ++k) {
        int j0 = jw + k * 32;
        // A-side garbage lanes (quad>=2) safe: B1 is exactly zero there.
        half4 cvs0 = ajs_g[(j0 + il) * 2 + h];
        half4 cvs1 = ajs_g[(j0 + 16 + il) * 2 + h];
        half4 cvb0 = ajb_g[(j0 + il) * 2 + h];
        half4 cvb1 = ajb_g[(j0 + 16 + il) * 2 + h];
        half4 cp0 = pfv[((j0 >> 4) * 16 + il) * 4 + quad];
        half4 cp1 = pfv[(((j0 >> 4) + 1) * 16 + il) * 4 + quad];

        GROUP(cvs0, cp0, b1s, acc_s);   // spatial, j 0..15
        GROUP(cvs1, cp1, b1s, acc_s);   // spatial, j 16..31
        GROUP(cvb0, cp0, b1b, acc_b);   // bilateral, j 0..15
        GROUP(cvb1, cp1, b1b, acc_b);   // bilateral, j 16..31
    }

    // ---- cross-wave reduction in LDS (conflict-free dump: r*64+lane) ----
    {
        float* rb = rbuf + w * 512;
#pragma unroll
        for (int r = 0; r < 4; ++r) {
            rb[r * 64 + lane]       = acc_s[r];
            rb[256 + r * 64 + lane] = acc_b[r];
        }
    }
    __syncthreads();
    if (t < 512) {
        float tot = 0.f;
#pragma unroll
        for (int w2 = 0; w2 < 16; ++w2) tot += rbuf[w2 * 512 + t];
        rbuf[t] = tot;   // slot t read only by thread t (w2=0 term)
    }
    __syncthreads();

    // ---- combine + compatibility + softmax for this block's 16 i's ----
    // D layout: value at rbuf[f*256 + r*64 + q16*16 + c], i = q16*4 + r.
    if (t < IBLK) {
        int i = i0 + t;
        int q16 = t >> 2, r = t & 3;
        int base = r * 64 + q16 * 16;
        float msg[C];
#pragma unroll
        for (int c = 0; c < C; ++c) {
            float m = 0.f;
#pragma unroll
            for (int kk = 0; kk < C; ++kk)
                m += SW[c * C + kk] * rbuf[base + kk] +
                     BW[c * C + kk] * rbuf[256 + base + kk];
            msg[c] = m;
        }
        float qq[C];
#pragma unroll
        for (int c = 0; c < C; ++c) {
            float pw = 0.f;
#pragma unroll
            for (int kk = 0; kk < C; ++kk) pw += CM[c * C + kk] * msg[kk];
            qq[c] = unaries[c * N + i] - pw;
        }
        if (is_last) {
#pragma unroll
            for (int c = 0; c < C; ++c) out[c * N + i] = qq[c];
        } else {
            float m = qq[0];
#pragma unroll
            for (int c = 1; c < C; ++c) m = fmaxf(m, qq[c]);
            float e[C], s = 0.0f;
#pragma unroll
            for (int c = 0; c < C; ++c) {
                e[c] = __builtin_amdgcn_exp2f((qq[c] - m) * LOG2E);
                s += e[c];
            }
            float inv = 1.0f / s;
#pragma unroll
            for (int c = 0; c < C; ++c) pf_out[PFIDX(i, c)] = (_Float16)(e[c] * inv);
        }
    }
}

extern "C" void kernel_launch(void* const* d_in, const int* in_sizes, int n_in,
                              void* d_out, int out_size, void* d_ws, size_t ws_size,
                              hipStream_t stream) {
    const float* unaries = (const float*)d_in[0];   // [10, 8192]
    const float* feat    = (const float*)d_in[1];   // [6, 8192]
    const float* SW      = (const float*)d_in[2];   // [10,10]
    const float* BW      = (const float*)d_in[3];   // [10,10]
    const float* CM      = (const float*)d_in[4];   // [10,10]
    float* out = (float*)d_out;

    char* ws = (char*)d_ws;
    half8* ajs    = (half8*)(ws + WS_AJS);
    half8* ajb    = (half8*)(ws + WS_AJB);
    _Float16* pf0 = (_Float16*)(ws + WS_PF0);
    _Float16* pf1 = (_Float16*)(ws + WS_PF1);

    init_kernel<<<N / 256, 256, 0, stream>>>(unaries, feat, ajs, ajb, pf0, pf1);
    const _Float16* pin = pf0;
    _Float16* pout = pf1;
    for (int it = 1; it <= NUM_ITERS; ++it) {
        fused_kernel<<<NBLK, FBLOCK, 0, stream>>>(
            unaries, feat, SW, BW, CM, (const half4*)ajs, (const half4*)ajb,
            pin, pout, out, it == NUM_ITERS ? 1 : 0);
        const _Float16* tmp = pout;
        pout = (_Float16*)pin;
        pin = tmp;
    }
}

// Round 10
// 166.098 us; speedup vs baseline: 1.1648x; 1.1648x over previous
//
#include <hip/hip_runtime.h>
#include <math.h>

#define N 8192
#define C 10
#define NUM_ITERS 5
#define FBLOCK 1024        /* 16 waves, 1 block/CU, 4 waves/SIMD, VGPR<=128 */
#define IBLK 32            /* i's per block */
#define NBLK (N / IBLK)    /* 256 blocks = 1 per CU */
#define JW (N / 16)        /* 512 j's per wave (contiguous slice) */
#define NS (JW / 32)       /* 16 s-iters per wave, 32 j's each */
#define LOG2E 1.44269504088896340736f
#define C3 (LOG2E / 64.0f)

typedef _Float16 half8 __attribute__((ext_vector_type(8)));
typedef _Float16 half4 __attribute__((ext_vector_type(4)));
typedef _Float16 half2 __attribute__((ext_vector_type(2)));
typedef float f32x4 __attribute__((ext_vector_type(4)));

// ws layout:
//   ajs half8[N]        128KB : j-side spatial aug [f*C3 x3, 0, 0,0,-h3*C3, 1]
//   ajb half8[N]        128KB : j-side bilateral aug [f*L2E x6, -h6*L2E, 1]
//   pf0 f16[N/16][16][16] 256KB : probs, J-TILED (tile jt, row c, col j&15); rows 10..15 zero
//   pf1 f16[N/16][16][16] 256KB : ping-pong partner
#define WS_AJS 0
#define WS_AJB (N * 16)
#define WS_PF0 (N * 32)
#define WS_PF1 (N * 64)
#define PFIDX(n, c) ((((n) >> 4) * 16 + (c)) * 16 + ((n) & 15))

static __device__ __forceinline__ half4 expcvt(f32x4 d) {
    float e0 = __builtin_amdgcn_exp2f(d[0]);
    float e1 = __builtin_amdgcn_exp2f(d[1]);
    float e2 = __builtin_amdgcn_exp2f(d[2]);
    float e3 = __builtin_amdgcn_exp2f(d[3]);
    half2 lo = __builtin_bit_cast(half2, __builtin_amdgcn_cvt_pkrtz(e0, e1));
    half2 hi = __builtin_bit_cast(half2, __builtin_amdgcn_cvt_pkrtz(e2, e3));
    half4 r = {lo[0], lo[1], hi[0], hi[1]};
    return r;
}

// operand bundle for one s-iter (named members only -> stays in registers)
struct Ops { half4 vs0, vs1, vb0, vb1, p0, p1; };
// GEMM1 results for one s-iter (8 fragments)
struct Dset { f32x4 d0, d1, d2, d3, d4, d5, d6, d7; };

// once per launch: aug features + softmax(unaries) -> pf0 (tiled); zero rows 10..15 both
__global__ __launch_bounds__(256) void init_kernel(
    const float* __restrict__ unaries, const float* __restrict__ feat,
    half8* __restrict__ ajs8, half8* __restrict__ ajb8,
    _Float16* __restrict__ pf0, _Float16* __restrict__ pf1) {
    int n = blockIdx.x * 256 + threadIdx.x;
    float f6[6];
#pragma unroll
    for (int d = 0; d < 6; ++d) f6[d] = feat[d * N + n];
    float h3 = 0.5f * (f6[0] * f6[0] + f6[1] * f6[1] + f6[2] * f6[2]);
    float h6v = h3 + 0.5f * (f6[3] * f6[3] + f6[4] * f6[4] + f6[5] * f6[5]);
    half8 a = {};
    a[0] = (_Float16)(f6[0] * C3);
    a[1] = (_Float16)(f6[1] * C3);
    a[2] = (_Float16)(f6[2] * C3);
    a[6] = (_Float16)(-h3 * C3);
    a[7] = (_Float16)1.0f;
    ajs8[n] = a;
    half8 b;
#pragma unroll
    for (int d = 0; d < 6; ++d) b[d] = (_Float16)(f6[d] * LOG2E);
    b[6] = (_Float16)(-h6v * LOG2E);
    b[7] = (_Float16)1.0f;
    ajb8[n] = b;

    float q[C];
#pragma unroll
    for (int c = 0; c < C; ++c) q[c] = unaries[c * N + n];
    float m = q[0];
#pragma unroll
    for (int c = 1; c < C; ++c) m = fmaxf(m, q[c]);
    float e[C], s = 0.0f;
#pragma unroll
    for (int c = 0; c < C; ++c) {
        e[c] = __builtin_amdgcn_exp2f((q[c] - m) * LOG2E);
        s += e[c];
    }
    float inv = 1.0f / s;
#pragma unroll
    for (int c = 0; c < C; ++c) pf0[PFIDX(n, c)] = (_Float16)(e[c] * inv);
#pragma unroll
    for (int c = C; c < 16; ++c) {
        pf0[PFIDX(n, c)] = (_Float16)0.0f;
        pf1[PFIDX(n, c)] = (_Float16)0.0f;
    }
}

// one dispatch per CRF iteration. Block owns 32 i's; wave w sweeps its 512-j
// slice, SOFTWARE-PIPELINED 2 s-iters deep: loads lead their use by ~1.5
// phases; GEMM1 results age one phase before exp/GEMM2 consumes them. The
// three streams (VMEM / MFMA / trans) are dependency-decoupled at every point.
__global__ __launch_bounds__(FBLOCK, 4) void fused_kernel(
    const float* __restrict__ unaries, const float* __restrict__ feat,
    const float* __restrict__ SW, const float* __restrict__ BW,
    const float* __restrict__ CM,
    const half4* __restrict__ ajs_g, const half4* __restrict__ ajb_g,
    const _Float16* __restrict__ pf_in, _Float16* __restrict__ pf_out,
    float* __restrict__ out, int is_last) {
    __shared__ float rbuf[16 * 1024];   // 64 KB, epilogue only
    int t = threadIdx.x;
    int i0 = blockIdx.x * IBLK;
    int lane = t & 63;
    int w = t >> 6;
    int il = lane & 15;
    int quad = lane >> 4;
    int h = quad & 1;
    bool klo = (quad < 2);
    const half4 hz = {};
    const f32x4 zero = {0.f, 0.f, 0.f, 0.f};

    // ---- i-side B1 fragments (32 i's, 2 subtiles of 16) ----
    half4 b1s0, b1s1, b1b0, b1b1;
#pragma unroll
    for (int s = 0; s < 2; ++s) {
        int i = i0 + s * 16 + il;
        float g0 = feat[0 * N + i], g1 = feat[1 * N + i], g2 = feat[2 * N + i];
        float g3 = feat[3 * N + i], g4 = feat[4 * N + i], g5 = feat[5 * N + i];
        float h3 = 0.5f * (g0 * g0 + g1 * g1 + g2 * g2);
        float h6v = h3 + 0.5f * (g3 * g3 + g4 * g4 + g5 * g5);
        half4 slo = {(_Float16)g0, (_Float16)g1, (_Float16)g2, (_Float16)0.0f};
        half4 shi = {(_Float16)0.0f, (_Float16)0.0f, (_Float16)1.0f, (_Float16)(-h3 * C3)};
        half4 blo = {(_Float16)g0, (_Float16)g1, (_Float16)g2, (_Float16)g3};
        half4 bhi = {(_Float16)g4, (_Float16)g5, (_Float16)1.0f, (_Float16)(-h6v * LOG2E)};
        half4 vs = klo ? (h ? shi : slo) : hz;
        half4 vb = klo ? (h ? bhi : blo) : hz;
        if (s == 0) { b1s0 = vs; b1b0 = vb; } else { b1s1 = vs; b1b1 = vb; }
    }

    f32x4 as0 = zero, as1 = zero, ab0 = zero, ab1 = zero;
    int jw = w * JW;
    const half4* pfv = (const half4*)pf_in;

    // load operands for s-iter k (wrap &15: harmless L2-hit reload near end)
#define LOAD_OPS(O, K)                                                     \
    {                                                                      \
        int _j0 = jw + ((K) & (NS - 1)) * 32;                              \
        O.vs0 = ajs_g[(_j0 + il) * 2 + h];                                 \
        O.vs1 = ajs_g[(_j0 + 16 + il) * 2 + h];                            \
        O.vb0 = ajb_g[(_j0 + il) * 2 + h];                                 \
        O.vb1 = ajb_g[(_j0 + 16 + il) * 2 + h];                            \
        O.p0 = pfv[((_j0 >> 4) * 16 + il) * 4 + quad];                     \
        O.p1 = pfv[(((_j0 >> 4) + 1) * 16 + il) * 4 + quad];               \
    }
    // A-side garbage lanes (quad>=2) safe: B1 is exactly zero there.
#define G1(D, O)                                                               \
    {                                                                          \
        D.d0 = __builtin_amdgcn_mfma_f32_16x16x16f16(O.vs0, b1s0, zero, 0, 0, 0); \
        D.d1 = __builtin_amdgcn_mfma_f32_16x16x16f16(O.vs0, b1s1, zero, 0, 0, 0); \
        D.d2 = __builtin_amdgcn_mfma_f32_16x16x16f16(O.vs1, b1s0, zero, 0, 0, 0); \
        D.d3 = __builtin_amdgcn_mfma_f32_16x16x16f16(O.vs1, b1s1, zero, 0, 0, 0); \
        D.d4 = __builtin_amdgcn_mfma_f32_16x16x16f16(O.vb0, b1b0, zero, 0, 0, 0); \
        D.d5 = __builtin_amdgcn_mfma_f32_16x16x16f16(O.vb0, b1b1, zero, 0, 0, 0); \
        D.d6 = __builtin_amdgcn_mfma_f32_16x16x16f16(O.vb1, b1b0, zero, 0, 0, 0); \
        D.d7 = __builtin_amdgcn_mfma_f32_16x16x16f16(O.vb1, b1b1, zero, 0, 0, 0); \
    }
#define G2(D, O)                                                               \
    {                                                                          \
        half4 _w0 = expcvt(D.d0), _w1 = expcvt(D.d1);                          \
        half4 _w2 = expcvt(D.d2), _w3 = expcvt(D.d3);                          \
        half4 _w4 = expcvt(D.d4), _w5 = expcvt(D.d5);                          \
        half4 _w6 = expcvt(D.d6), _w7 = expcvt(D.d7);                          \
        as0 = __builtin_amdgcn_mfma_f32_16x16x16f16(_w0, O.p0, as0, 0, 0, 0);  \
        as1 = __builtin_amdgcn_mfma_f32_16x16x16f16(_w1, O.p0, as1, 0, 0, 0);  \
        as0 = __builtin_amdgcn_mfma_f32_16x16x16f16(_w2, O.p1, as0, 0, 0, 0);  \
        as1 = __builtin_amdgcn_mfma_f32_16x16x16f16(_w3, O.p1, as1, 0, 0, 0);  \
        ab0 = __builtin_amdgcn_mfma_f32_16x16x16f16(_w4, O.p0, ab0, 0, 0, 0);  \
        ab1 = __builtin_amdgcn_mfma_f32_16x16x16f16(_w5, O.p0, ab1, 0, 0, 0);  \
        ab0 = __builtin_amdgcn_mfma_f32_16x16x16f16(_w6, O.p1, ab0, 0, 0, 0);  \
        ab1 = __builtin_amdgcn_mfma_f32_16x16x16f16(_w7, O.p1, ab1, 0, 0, 0);  \
    }

    Ops opA, opB;
    Dset dd;
    // ---- prologue: s-iters 0,1 operands; GEMM1(0) ----
    LOAD_OPS(opA, 0);
    LOAD_OPS(opB, 1);
    G1(dd, opA);

    // steady state: 7 iterations x 2 s-iters; program order keeps every
    // consumer >= 1 full phase behind its producer.
    for (int m = 0; m < 7; ++m) {
        G2(dd, opA);            // finish s-iter 2m   (dd, opA.p from >=1 phase ago)
        LOAD_OPS(opA, 2 * m + 2);   // lead use by ~1.5 phases
        G1(dd, opB);            // s-iter 2m+1 GEMM1  (opB loaded >=2 phases ago)
        G2(dd, opB);            // s-iter 2m+1 finish (only short exp->GEMM2 hop)
        LOAD_OPS(opB, 2 * m + 3);
        G1(dd, opA);            // s-iter 2m+2 GEMM1 (opA from this iteration)
    }
    // ---- epilogue: s-iters 14,15 ----
    G2(dd, opA);
    G1(dd, opB);
    G2(dd, opB);

#undef LOAD_OPS
#undef G1
#undef G2

    // ---- cross-wave reduction in LDS (conflict-free dump: r*64+lane) ----
    {
        float* rb = rbuf + w * 1024;
#pragma unroll
        for (int r = 0; r < 4; ++r) {
            rb[r * 64 + lane]       = as0[r];
            rb[256 + r * 64 + lane] = as1[r];
            rb[512 + r * 64 + lane] = ab0[r];
            rb[768 + r * 64 + lane] = ab1[r];
        }
    }
    __syncthreads();
    {
        float tot = 0.f;
#pragma unroll
        for (int w2 = 0; w2 < 16; ++w2) tot += rbuf[w2 * 1024 + t];
        rbuf[t] = tot;   // slot t read only by thread t (w2=0 term)
    }
    __syncthreads();

    // ---- combine + compatibility + softmax for this block's 32 i's ----
    if (t < IBLK) {
        int i = i0 + t;
        int sub = t >> 4, ql = (t & 15) >> 2, rr = t & 3;
        float sp[C], bl[C];
#pragma unroll
        for (int c = 0; c < C; ++c) {
            int base = sub * 256 + rr * 64 + ql * 16 + c;
            sp[c] = rbuf[base];
            bl[c] = rbuf[base + 512];
        }
        float msg[C];
#pragma unroll
        for (int c = 0; c < C; ++c) {
            float m = 0.f;
#pragma unroll
            for (int k = 0; k < C; ++k)
                m += SW[c * C + k] * sp[k] + BW[c * C + k] * bl[k];
            msg[c] = m;
        }
        float qq[C];
#pragma unroll
        for (int c = 0; c < C; ++c) {
            float pw = 0.f;
#pragma unroll
            for (int k = 0; k < C; ++k) pw += CM[c * C + k] * msg[k];
            qq[c] = unaries[c * N + i] - pw;
        }
        if (is_last) {
#pragma unroll
            for (int c = 0; c < C; ++c) out[c * N + i] = qq[c];
        } else {
            float m = qq[0];
#pragma unroll
            for (int c = 1; c < C; ++c) m = fmaxf(m, qq[c]);
            float e[C], s = 0.0f;
#pragma unroll
            for (int c = 0; c < C; ++c) {
                e[c] = __builtin_amdgcn_exp2f((qq[c] - m) * LOG2E);
                s += e[c];
            }
            float inv = 1.0f / s;
#pragma unroll
            for (int c = 0; c < C; ++c) pf_out[PFIDX(i, c)] = (_Float16)(e[c] * inv);
        }
    }
}

extern "C" void kernel_launch(void* const* d_in, const int* in_sizes, int n_in,
                              void* d_out, int out_size, void* d_ws, size_t ws_size,
                              hipStream_t stream) {
    const float* unaries = (const float*)d_in[0];   // [10, 8192]
    const float* feat    = (const float*)d_in[1];   // [6, 8192]
    const float* SW      = (const float*)d_in[2];   // [10,10]
    const float* BW      = (const float*)d_in[3];   // [10,10]
    const float* CM      = (const float*)d_in[4];   // [10,10]
    float* out = (float*)d_out;

    char* ws = (char*)d_ws;
    half8* ajs    = (half8*)(ws + WS_AJS);
    half8* ajb    = (half8*)(ws + WS_AJB);
    _Float16* pf0 = (_Float16*)(ws + WS_PF0);
    _Float16* pf1 = (_Float16*)(ws + WS_PF1);

    init_kernel<<<N / 256, 256, 0, stream>>>(unaries, feat, ajs, ajb, pf0, pf1);
    const _Float16* pin = pf0;
    _Float16* pout = pf1;
    for (int it = 1; it <= NUM_ITERS; ++it) {
        fused_kernel<<<NBLK, FBLOCK, 0, stream>>>(
            unaries, feat, SW, BW, CM, (const half4*)ajs, (const half4*)ajb,
            pin, pout, out, it == NUM_ITERS ? 1 : 0);
        const _Float16* tmp = pout;
        pout = (_Float16*)pin;
        pin = tmp;
    }
}